// Round 4
// baseline (1023.919 us; speedup 1.0000x reference)
//
#include <hip/hip_runtime.h>
#include <math.h>
#include <stdint.h>

// Fused pipeline (E=300000, ND=100000, FEAT=256, RDIM=128):
//   prep:   weights -> bf16; cnt=0
//   CSR:    hist, scan, scan_bsum, add_offsets, build_eidx (sort edges by dst)
//   gather: rid_s[i]=rid[eidx[i]], esrc_s[i]=esrc[eidx[i]]
//   fused:  per 32 sorted edges/wave, ALL IN REGISTERS:
//             s1 (swapped mfma, K=128): acc=W1·remb_row^T + fused pa/ra dots
//             s2 (swapped, K=256):      acc=W2·gelu(t)^T   (t from regs via shfl_xor(32))
//             s3 (normal,  K=256):      rf = t·W3^T ; m = feat[src]*ga + rf*gb -> m[i] (sorted)
//   segsum: h[d] = sum of contiguous m rows (CSR ranges)
//   g4:     out = (h @ lin_w^T)*ci + b
// mfma_f32_32x32x16_bf16 layouts (validated on-HW by R2/R3 passing):
//   A: row=lane&31, k=8*(lane>>5)+j ; B: col=lane&31, same k
//   D: col=lane&31, row=(reg&3)+8*(reg>>2)+4*(lane>>5)
// Swapped stages (W as A): lane's D-regs = 16 feats (8p+4kg+r pattern) of edge i0+l31.

typedef short bf16x8 __attribute__((ext_vector_type(8)));
typedef float f32x16 __attribute__((ext_vector_type(16)));

__device__ __forceinline__ float bf2f(unsigned short v) {
    union { unsigned int u; float f; } x; x.u = ((unsigned int)v) << 16; return x.f;
}
__device__ __forceinline__ unsigned short f2bf(float f) {
    union { float f; unsigned int u; } x; x.f = f;
    unsigned int u = x.u;
    return (unsigned short)((u + 0x7FFFu + ((u >> 16) & 1u)) >> 16);
}
__device__ __forceinline__ unsigned pack2(float lo, float hi) {
    return (unsigned)f2bf(lo) | ((unsigned)f2bf(hi) << 16);
}
__device__ __forceinline__ float gelu_erf(float x) {
    return 0.5f * x * (1.0f + erff(x * 0.70710678118654752f));
}
__device__ __forceinline__ float sigmoidf(float x) {
    return 1.0f / (1.0f + expf(-x));
}

__global__ __launch_bounds__(256) void prep_weights(
    const float* __restrict__ rw1, const float* __restrict__ rw2,
    const float* __restrict__ rw3, const float* __restrict__ lw,
    unsigned short* __restrict__ w1b, unsigned short* __restrict__ w2b,
    unsigned short* __restrict__ w3b, unsigned short* __restrict__ lwb)
{
    int i = blockIdx.x * blockDim.x + threadIdx.x;
    if (i < 256 * 128) w1b[i] = f2bf(rw1[i]);
    if (i < 256 * 256) {
        w2b[i] = f2bf(rw2[i]);
        w3b[i] = f2bf(rw3[i]);
        lwb[i] = f2bf(lw[i]);
    }
}

// ---------------- CSR build ----------------
__global__ __launch_bounds__(256) void hist_kernel(
    const int* __restrict__ edst, int* __restrict__ cnt,
    int* __restrict__ within, int E)
{
    int e = blockIdx.x * blockDim.x + threadIdx.x;
    if (e < E) within[e] = atomicAdd(&cnt[edst[e]], 1);
}

__global__ __launch_bounds__(1024) void scan_block(
    const int* __restrict__ cnt, int* __restrict__ start,
    int* __restrict__ bsum, int n)
{
    __shared__ int s[1024];
    int gid = blockIdx.x * 1024 + threadIdx.x;
    int v = (gid < n) ? cnt[gid] : 0;
    s[threadIdx.x] = v;
    __syncthreads();
    #pragma unroll
    for (int off = 1; off < 1024; off <<= 1) {
        int t = (threadIdx.x >= off) ? s[threadIdx.x - off] : 0;
        __syncthreads();
        if (threadIdx.x >= off) s[threadIdx.x] += t;
        __syncthreads();
    }
    if (gid < n) start[gid] = s[threadIdx.x] - v;   // exclusive
    if (threadIdx.x == 1023) bsum[blockIdx.x] = s[1023];
}

__global__ void scan_bsum(int* __restrict__ bsum, int nb) {
    if (threadIdx.x == 0 && blockIdx.x == 0) {
        int acc = 0;
        for (int i = 0; i < nb; ++i) { int v = bsum[i]; bsum[i] = acc; acc += v; }
    }
}

__global__ __launch_bounds__(1024) void add_offsets(
    int* __restrict__ start, const int* __restrict__ bsum, int n, int E)
{
    int gid = blockIdx.x * 1024 + threadIdx.x;
    if (gid < n) start[gid] += bsum[gid >> 10];
    if (gid == 0) start[n] = E;
}

__global__ __launch_bounds__(256) void build_eidx(
    const int* __restrict__ edst, const int* __restrict__ within,
    const int* __restrict__ start, int* __restrict__ eidx, int E)
{
    int e = blockIdx.x * blockDim.x + threadIdx.x;
    if (e < E) eidx[start[edst[e]] + within[e]] = e;
}

__global__ __launch_bounds__(256) void gather_sorted(
    const int* __restrict__ eidx, const int* __restrict__ rid,
    const int* __restrict__ esrc, int* __restrict__ rid_s,
    int* __restrict__ esrc_s, int E)
{
    int t = blockIdx.x * blockDim.x + threadIdx.x;
    if (t < E) { int e = eidx[t]; rid_s[t] = rid[e]; esrc_s[t] = esrc[e]; }
}

// ---------------- fused g1+g2+g3 ----------------
__global__ __launch_bounds__(256, 2) void fused_edge(
    const float* __restrict__ remb, const int* __restrict__ rid_s,
    const int* __restrict__ esrc_s,
    const unsigned short* __restrict__ w1b, const unsigned short* __restrict__ w2b,
    const unsigned short* __restrict__ w3b,
    const float* __restrict__ pw, const float* __restrict__ sw,
    const float* __restrict__ cj, const float* __restrict__ feat,
    unsigned short* __restrict__ m, int E)
{
    const int lane = threadIdx.x & 63;
    const int wid  = threadIdx.x >> 6;
    const int l31  = lane & 31;
    const int kg   = lane >> 5;                  // 0..1
    const int i0   = blockIdx.x * 128 + wid * 32; // wave's first sorted-edge
    if (i0 >= E) return;
    const int i  = i0 + l31;                      // lane's edge (E%32==0 -> valid)
    const int ic = (i < E) ? i : (E - 1);
    const int rid0 = rid_s[ic];
    const int src0 = esrc_s[ic];

    // t_pk[n][p][h]: u32 = bf16 pair of feats {n*32+8p+4kg+2h, +1} of edge i
    unsigned tpk[8][4][2];
    float ga, gb;

    // ---- stage 1: swapped, K=128, fused pa/ra dots ----
    {
        f32x16 acc[8];
        #pragma unroll
        for (int n = 0; n < 8; ++n) acc[n] = (f32x16)0.0f;
        float pd = 0.f, rd = 0.f;
        #pragma unroll
        for (int ks = 0; ks < 8; ++ks) {
            const int kk = ks * 16 + kg * 8;
            const float* rp = remb + (size_t)rid0 * 128 + kk;
            float4 u0 = *(const float4*)rp;
            float4 u1 = *(const float4*)(rp + 4);
            float4 p0 = *(const float4*)(pw + kk);
            float4 p1 = *(const float4*)(pw + kk + 4);
            float4 s0 = *(const float4*)(sw + kk);
            float4 s1 = *(const float4*)(sw + kk + 4);
            pd += u0.x*p0.x + u0.y*p0.y + u0.z*p0.z + u0.w*p0.w
                + u1.x*p1.x + u1.y*p1.y + u1.z*p1.z + u1.w*p1.w;
            rd += u0.x*s0.x + u0.y*s0.y + u0.z*s0.z + u0.w*s0.w
                + u1.x*s1.x + u1.y*s1.y + u1.z*s1.z + u1.w*s1.w;
            union { unsigned u[4]; bf16x8 v; } bu;
            bu.u[0] = pack2(u0.x, u0.y); bu.u[1] = pack2(u0.z, u0.w);
            bu.u[2] = pack2(u1.x, u1.y); bu.u[3] = pack2(u1.z, u1.w);
            bf16x8 tf = bu.v;
            #pragma unroll
            for (int n = 0; n < 8; ++n) {
                bf16x8 wf = *(const bf16x8*)(w1b + (size_t)(n*32 + l31)*128 + kk);
                acc[n] = __builtin_amdgcn_mfma_f32_32x32x16_bf16(wf, tf, acc[n], 0, 0, 0);
            }
        }
        pd += __shfl_xor(pd, 32);
        rd += __shfl_xor(rd, 32);
        float cjv = cj[src0];
        ga = sigmoidf(pd) * cjv;
        gb = sigmoidf(rd) * cjv;
        #pragma unroll
        for (int n = 0; n < 8; ++n)
            #pragma unroll
            for (int p = 0; p < 4; ++p)
                #pragma unroll
                for (int hh = 0; hh < 2; ++hh)
                    tpk[n][p][hh] = pack2(gelu_erf(acc[n][4*p + 2*hh]),
                                          gelu_erf(acc[n][4*p + 2*hh + 1]));
    }

    // ---- stage 2: swapped, K=256, t-frags from tpk via shfl_xor(32) ----
    {
        f32x16 acc[8];
        #pragma unroll
        for (int n = 0; n < 8; ++n) acc[n] = (f32x16)0.0f;
        #pragma unroll
        for (int ks = 0; ks < 16; ++ks) {
            const int k0 = ks * 16;
            const int n0 = k0 >> 5,       p0 = (k0 >> 3) & 3;       // kg0's octet
            const int n1 = (k0 + 8) >> 5, p1 = ((k0 + 8) >> 3) & 3; // kg1's octet
            unsigned s0 = kg ? tpk[n0][p0][0] : tpk[n1][p1][0];
            unsigned s1 = kg ? tpk[n0][p0][1] : tpk[n1][p1][1];
            unsigned r0 = (unsigned)__shfl_xor((int)s0, 32);
            unsigned r1 = (unsigned)__shfl_xor((int)s1, 32);
            union { unsigned u[4]; bf16x8 v; } bu;
            bu.u[0] = kg ? r0 : tpk[n0][p0][0];
            bu.u[1] = kg ? r1 : tpk[n0][p0][1];
            bu.u[2] = kg ? tpk[n1][p1][0] : r0;
            bu.u[3] = kg ? tpk[n1][p1][1] : r1;
            bf16x8 tf = bu.v;
            const int kk = k0 + kg * 8;
            #pragma unroll
            for (int n = 0; n < 8; ++n) {
                bf16x8 wf = *(const bf16x8*)(w2b + (size_t)(n*32 + l31)*256 + kk);
                acc[n] = __builtin_amdgcn_mfma_f32_32x32x16_bf16(wf, tf, acc[n], 0, 0, 0);
            }
        }
        #pragma unroll
        for (int n = 0; n < 8; ++n)
            #pragma unroll
            for (int p = 0; p < 4; ++p)
                #pragma unroll
                for (int hh = 0; hh < 2; ++hh)
                    tpk[n][p][hh] = pack2(gelu_erf(acc[n][4*p + 2*hh]),
                                          gelu_erf(acc[n][4*p + 2*hh + 1]));
    }

    // ---- stage 3: normal orientation (t as A, W3 as B), K=256 ----
    {
        f32x16 acc[8];
        #pragma unroll
        for (int n = 0; n < 8; ++n) acc[n] = (f32x16)0.0f;
        #pragma unroll
        for (int ks = 0; ks < 16; ++ks) {
            const int k0 = ks * 16;
            const int n0 = k0 >> 5,       p0 = (k0 >> 3) & 3;
            const int n1 = (k0 + 8) >> 5, p1 = ((k0 + 8) >> 3) & 3;
            unsigned s0 = kg ? tpk[n0][p0][0] : tpk[n1][p1][0];
            unsigned s1 = kg ? tpk[n0][p0][1] : tpk[n1][p1][1];
            unsigned r0 = (unsigned)__shfl_xor((int)s0, 32);
            unsigned r1 = (unsigned)__shfl_xor((int)s1, 32);
            union { unsigned u[4]; bf16x8 v; } bu;
            bu.u[0] = kg ? r0 : tpk[n0][p0][0];
            bu.u[1] = kg ? r1 : tpk[n0][p0][1];
            bu.u[2] = kg ? tpk[n1][p1][0] : r0;
            bu.u[3] = kg ? tpk[n1][p1][1] : r1;
            bf16x8 tf = bu.v;
            const int kk = k0 + kg * 8;
            #pragma unroll
            for (int n = 0; n < 8; ++n) {
                bf16x8 wf = *(const bf16x8*)(w3b + (size_t)(n*32 + l31)*256 + kk);
                acc[n] = __builtin_amdgcn_mfma_f32_32x32x16_bf16(tf, wf, acc[n], 0, 0, 0);
            }
        }
        // epilogue: m[i] = feat[src]*ga + rf*gb, rows = sorted order (coalesced)
        #pragma unroll
        for (int p = 0; p < 4; ++p) {
            #pragma unroll
            for (int r = 0; r < 4; ++r) {
                const int reg  = 4 * p + r;
                const int eoff = r + 8 * p + 4 * kg;   // 0..31
                const int ii   = i0 + eoff;
                float gav = __shfl(ga, eoff);
                float gbv = __shfl(gb, eoff);
                int   sv  = __shfl(src0, eoff);
                if (ii < E) {
                    #pragma unroll
                    for (int n = 0; n < 8; ++n) {
                        const int col = n * 32 + l31;
                        float fv  = feat[(size_t)sv * 256 + col];
                        float val = fv * gav + acc[n][reg] * gbv;
                        m[(size_t)ii * 256 + col] = f2bf(val);
                    }
                }
            }
        }
    }
}

// ---------------- segment sum over sorted m: one wave per dst ----------------
__global__ __launch_bounds__(256) void segsum_kernel(
    const int* __restrict__ start, const unsigned short* __restrict__ m,
    unsigned short* __restrict__ h, int ND)
{
    int d = blockIdx.x * 4 + (threadIdx.x >> 6);
    if (d >= ND) return;
    int lane = threadIdx.x & 63;
    int s0 = start[d], s1 = start[d + 1];
    float a0 = 0.f, a1 = 0.f, a2 = 0.f, a3 = 0.f;
    for (int i = s0; i < s1; ++i) {
        ushort4 v = *(const ushort4*)(m + (size_t)i * 256 + lane * 4);
        a0 += bf2f(v.x); a1 += bf2f(v.y); a2 += bf2f(v.z); a3 += bf2f(v.w);
    }
    ushort4 o; o.x = f2bf(a0); o.y = f2bf(a1); o.z = f2bf(a2); o.w = f2bf(a3);
    *(ushort4*)(h + (size_t)d * 256 + lane * 4) = o;
}

// ---------------- g4: out = (h @ lin_w^T)*ci + b ----------------
__global__ __launch_bounds__(256, 2) void g4_kernel(
    const unsigned short* __restrict__ Ab, const unsigned short* __restrict__ Wb,
    float* __restrict__ outf, const float* __restrict__ ci,
    const float* __restrict__ bias, int M)
{
    const int lane = threadIdx.x & 63;
    const int wid  = threadIdx.x >> 6;
    const int l31  = lane & 31;
    const int kg   = lane >> 5;
    const int colh = (wid & 1) * 128;
    const int wbase = blockIdx.x * 128 + (wid >> 1) * 64;
    const int r0 = wbase + l31, r1 = wbase + 32 + l31;
    const int ar0 = (r0 < M) ? r0 : (M - 1);
    const int ar1 = (r1 < M) ? r1 : (M - 1);

    f32x16 acc[2][4];
    #pragma unroll
    for (int mi = 0; mi < 2; ++mi)
        #pragma unroll
        for (int n = 0; n < 4; ++n) acc[mi][n] = (f32x16)0.0f;

    for (int k0 = 0; k0 < 256; k0 += 16) {
        const int kk = k0 + kg * 8;
        bf16x8 a0 = *(const bf16x8*)(Ab + (size_t)ar0 * 256 + kk);
        bf16x8 a1 = *(const bf16x8*)(Ab + (size_t)ar1 * 256 + kk);
        const unsigned short* wbp = Wb + (size_t)(colh + l31) * 256 + kk;
        #pragma unroll
        for (int n = 0; n < 4; ++n) {
            bf16x8 b = *(const bf16x8*)(wbp + (size_t)(n * 32) * 256);
            acc[0][n] = __builtin_amdgcn_mfma_f32_32x32x16_bf16(a0, b, acc[0][n], 0, 0, 0);
            acc[1][n] = __builtin_amdgcn_mfma_f32_32x32x16_bf16(a1, b, acc[1][n], 0, 0, 0);
        }
    }
    #pragma unroll
    for (int mi = 0; mi < 2; ++mi) {
        #pragma unroll
        for (int r = 0; r < 16; ++r) {
            const int gr = wbase + mi * 32 + (r & 3) + 8 * (r >> 2) + 4 * kg;
            if (gr >= M) continue;
            float civ = ci[gr];
            #pragma unroll
            for (int n = 0; n < 4; ++n) {
                int col = colh + n * 32 + l31;
                outf[(size_t)gr * 256 + col] = acc[mi][n][r] * civ + bias[col];
            }
        }
    }
}

extern "C" void kernel_launch(void* const* d_in, const int* in_sizes, int n_in,
                              void* d_out, int out_size, void* d_ws, size_t ws_size,
                              hipStream_t stream) {
    const float* feat = (const float*)d_in[0];
    const float* cj   = (const float*)d_in[1];
    const float* ci   = (const float*)d_in[2];
    const int*   esrc = (const int*)d_in[3];
    const int*   edst = (const int*)d_in[4];
    const int*   rid  = (const int*)d_in[5];
    const float* remb = (const float*)d_in[6];
    const float* pw   = (const float*)d_in[7];
    const float* sw   = (const float*)d_in[8];
    const float* rw1  = (const float*)d_in[9];
    const float* rw2  = (const float*)d_in[10];
    const float* rw3  = (const float*)d_in[11];
    const float* lw   = (const float*)d_in[12];
    const float* lb   = (const float*)d_in[13];
    float* out = (float*)d_out;

    const int E  = in_sizes[3];   // 300000
    const int ND = in_sizes[2];   // 100000

    // workspace carve-up
    char* ws = (char*)d_ws;
    unsigned short* m   = (unsigned short*)ws;            // E*256 bf16
    unsigned short* h   = m + (size_t)E * 256;            // ND*256 bf16
    unsigned short* w1b = h + (size_t)ND * 256;           // 256*128
    unsigned short* w2b = w1b + 256 * 128;                // 256*256
    unsigned short* w3b = w2b + 256 * 256;
    unsigned short* lwb = w3b + 256 * 256;
    int* cnt    = (int*)(lwb + 256 * 256);                // ND
    int* start  = cnt + ND;                               // ND+1
    int* bsum   = start + ND + 1;                         // 128
    int* within = bsum + 128;                             // E
    int* eidx   = within + E;                             // E
    int* rid_s  = eidx + E;                               // E
    int* esrc_s = rid_s + E;                              // E

    const int NB = (ND + 1023) / 1024;

    hipMemsetAsync(cnt, 0, (size_t)ND * sizeof(int), stream);
    prep_weights<<<256, 256, 0, stream>>>(rw1, rw2, rw3, lw, w1b, w2b, w3b, lwb);

    // CSR build + sorted-edge gathers
    hist_kernel<<<(E + 255) / 256, 256, 0, stream>>>(edst, cnt, within, E);
    scan_block<<<NB, 1024, 0, stream>>>(cnt, start, bsum, ND);
    scan_bsum<<<1, 64, 0, stream>>>(bsum, NB);
    add_offsets<<<NB, 1024, 0, stream>>>(start, bsum, ND, E);
    build_eidx<<<(E + 255) / 256, 256, 0, stream>>>(edst, within, start, eidx, E);
    gather_sorted<<<(E + 255) / 256, 256, 0, stream>>>(eidx, rid, esrc, rid_s, esrc_s, E);

    // fused g1+g2+g3 (t never leaves registers)
    fused_edge<<<(E + 127) / 128, 256, 0, stream>>>(
        remb, rid_s, esrc_s, w1b, w2b, w3b, pw, sw, cj, feat, m, E);

    // segsum over contiguous sorted rows
    segsum_kernel<<<(ND + 3) / 4, 256, 0, stream>>>(start, m, h, ND);

    // g4
    g4_kernel<<<(ND + 127) / 128, 256, 0, stream>>>(h, lwb, out, ci, lb, ND);
}

// Round 5
// 711.389 us; speedup vs baseline: 1.4393x; 1.4393x over previous
//
#include <hip/hip_runtime.h>
#include <math.h>
#include <stdint.h>

// Fused pipeline (E=300000, ND=100000, FEAT=256, RDIM=128):
//   prep:   weights -> bf16; cnt=0
//   CSR:    hist, scan, scan_bsum, add_offsets, build_eidx (sort edges by dst)
//   gather: rid_s[i]=rid[eidx[i]], esrc_s[i]=esrc[eidx[i]]
//   fused (one kernel, t staged in 64KB LDS, 128 edges/block):
//     s1 (swapped mfma, K=128): t1 = gelu(W1 @ remb_row), + pa/ra dots -> ga/gb
//     s2 (swapped, K=256):      t2 = gelu(W2 @ t1)        (LDS in-place per-wave rows)
//     s3 (normal,  K=256):      rf = t2 @ W3^T ; m = feat[src]*ga + rf*gb  (coalesced)
//   segsum: h[d] = sum of contiguous m rows (CSR ranges)
//   g4:     out = (h @ lin_w^T)*ci + b
// mfma_f32_32x32x16_bf16 layouts (HW-validated by R2-R4 passing):
//   A: row=lane&31, k=8*(lane>>5)+j ; B: col=lane&31, same k
//   D: col=lane&31, row=(reg&3)+8*(reg>>2)+4*(lane>>5)
// LDS t: row=local edge (128), 512B/row, XOR swizzle byte^=((row&7)<<4) on both sides.

typedef short bf16x8 __attribute__((ext_vector_type(8)));
typedef float f32x16 __attribute__((ext_vector_type(16)));

__device__ __forceinline__ float bf2f(unsigned short v) {
    union { unsigned int u; float f; } x; x.u = ((unsigned int)v) << 16; return x.f;
}
__device__ __forceinline__ unsigned short f2bf(float f) {
    union { float f; unsigned int u; } x; x.f = f;
    unsigned int u = x.u;
    return (unsigned short)((u + 0x7FFFu + ((u >> 16) & 1u)) >> 16);
}
__device__ __forceinline__ unsigned pack2(float lo, float hi) {
    return (unsigned)f2bf(lo) | ((unsigned)f2bf(hi) << 16);
}
__device__ __forceinline__ float gelu_erf(float x) {
    return 0.5f * x * (1.0f + erff(x * 0.70710678118654752f));
}
__device__ __forceinline__ float sigmoidf(float x) {
    return 1.0f / (1.0f + expf(-x));
}

__global__ __launch_bounds__(256) void prep_weights(
    const float* __restrict__ rw1, const float* __restrict__ rw2,
    const float* __restrict__ rw3, const float* __restrict__ lw,
    unsigned short* __restrict__ w1b, unsigned short* __restrict__ w2b,
    unsigned short* __restrict__ w3b, unsigned short* __restrict__ lwb)
{
    int i = blockIdx.x * blockDim.x + threadIdx.x;
    if (i < 256 * 128) w1b[i] = f2bf(rw1[i]);
    if (i < 256 * 256) {
        w2b[i] = f2bf(rw2[i]);
        w3b[i] = f2bf(rw3[i]);
        lwb[i] = f2bf(lw[i]);
    }
}

// ---------------- CSR build ----------------
__global__ __launch_bounds__(256) void hist_kernel(
    const int* __restrict__ edst, int* __restrict__ cnt,
    int* __restrict__ within, int E)
{
    int e = blockIdx.x * blockDim.x + threadIdx.x;
    if (e < E) within[e] = atomicAdd(&cnt[edst[e]], 1);
}

__global__ __launch_bounds__(1024) void scan_block(
    const int* __restrict__ cnt, int* __restrict__ start,
    int* __restrict__ bsum, int n)
{
    __shared__ int s[1024];
    int gid = blockIdx.x * 1024 + threadIdx.x;
    int v = (gid < n) ? cnt[gid] : 0;
    s[threadIdx.x] = v;
    __syncthreads();
    #pragma unroll
    for (int off = 1; off < 1024; off <<= 1) {
        int t = (threadIdx.x >= off) ? s[threadIdx.x - off] : 0;
        __syncthreads();
        if (threadIdx.x >= off) s[threadIdx.x] += t;
        __syncthreads();
    }
    if (gid < n) start[gid] = s[threadIdx.x] - v;   // exclusive
    if (threadIdx.x == 1023) bsum[blockIdx.x] = s[1023];
}

__global__ void scan_bsum(int* __restrict__ bsum, int nb) {
    if (threadIdx.x == 0 && blockIdx.x == 0) {
        int acc = 0;
        for (int i = 0; i < nb; ++i) { int v = bsum[i]; bsum[i] = acc; acc += v; }
    }
}

__global__ __launch_bounds__(1024) void add_offsets(
    int* __restrict__ start, const int* __restrict__ bsum, int n, int E)
{
    int gid = blockIdx.x * 1024 + threadIdx.x;
    if (gid < n) start[gid] += bsum[gid >> 10];
    if (gid == 0) start[n] = E;
}

__global__ __launch_bounds__(256) void build_eidx(
    const int* __restrict__ edst, const int* __restrict__ within,
    const int* __restrict__ start, int* __restrict__ eidx, int E)
{
    int e = blockIdx.x * blockDim.x + threadIdx.x;
    if (e < E) eidx[start[edst[e]] + within[e]] = e;
}

__global__ __launch_bounds__(256) void gather_sorted(
    const int* __restrict__ eidx, const int* __restrict__ rid,
    const int* __restrict__ esrc, int* __restrict__ rid_s,
    int* __restrict__ esrc_s, int E)
{
    int t = blockIdx.x * blockDim.x + threadIdx.x;
    if (t < E) { int e = eidx[t]; rid_s[t] = rid[e]; esrc_s[t] = esrc[e]; }
}

// ---------------- LDS t helpers (XOR swizzled) ----------------
__device__ __forceinline__ bf16x8 ldtf(const unsigned short* t_lds, int row, int ks, int kg) {
    int off = (row * 512 + ks * 32 + kg * 16) ^ ((row & 7) << 4);
    return *(const bf16x8*)((const char*)t_lds + off);
}
__device__ __forceinline__ void sttf(unsigned short* t_lds, int row, int n, int p, int kg, uint2 w) {
    int off = (row * 512 + n * 64 + 16 * p + 8 * kg) ^ ((row & 7) << 4);
    *(uint2*)((char*)t_lds + off) = w;
}

template <int NW>
__device__ __forceinline__ void load_wfrags(bf16x8* wf, const unsigned short* __restrict__ Wb,
                                            int rowbase, int Kstride, int kk) {
    #pragma unroll
    for (int n = 0; n < NW; ++n)
        wf[n] = *(const bf16x8*)(Wb + (size_t)(rowbase + n * 32) * Kstride + kk);
}

// ---------------- fused g1+g2+g3 ----------------
__global__ __launch_bounds__(256, 2) void fused_edge(
    const float* __restrict__ remb, const int* __restrict__ rid_s,
    const int* __restrict__ esrc_s,
    const unsigned short* __restrict__ w1b, const unsigned short* __restrict__ w2b,
    const unsigned short* __restrict__ w3b,
    const float* __restrict__ pw, const float* __restrict__ sw,
    const float* __restrict__ cj, const float* __restrict__ feat,
    float* __restrict__ ga, float* __restrict__ gb,
    unsigned short* __restrict__ m, int E)
{
    __shared__ __align__(16) unsigned short t_lds[128 * 256];   // 64 KB

    const int lane = threadIdx.x & 63;
    const int wid  = threadIdx.x >> 6;
    const int l31  = lane & 31;
    const int kg   = lane >> 5;                   // 0..1
    const int blk0 = blockIdx.x * 128;
    const int i0   = blk0 + wid * 32;             // wave's first sorted-edge
    const int i    = i0 + l31;                    // lane's edge
    const int ic   = (i < E) ? i : (E - 1);
    const int rid0 = rid_s[ic];
    const int src0 = esrc_s[ic];
    const int row_l = wid * 32 + l31;             // local LDS row (this lane's edge)

    // ================= stage 1: swapped, K=128, fused pa/ra =================
    {
        f32x16 acc[8];
        #pragma unroll
        for (int n = 0; n < 8; ++n) acc[n] = (f32x16)0.0f;
        float pd = 0.f, rd = 0.f;

        float4 cu0, cu1;
        {
            const float* rp = remb + (size_t)rid0 * 128 + kg * 8;
            cu0 = *(const float4*)rp; cu1 = *(const float4*)(rp + 4);
        }
        bf16x8 wfc[8];
        load_wfrags<8>(wfc, w1b, l31, 128, kg * 8);

        #pragma unroll
        for (int ks = 0; ks < 8; ++ks) {
            const int kk = ks * 16 + kg * 8;
            float4 nu0 = cu0, nu1 = cu1;
            bf16x8 wfn[8];
            if (ks < 7) {
                const float* rp = remb + (size_t)rid0 * 128 + kk + 16;
                nu0 = *(const float4*)rp; nu1 = *(const float4*)(rp + 4);
                load_wfrags<8>(wfn, w1b, l31, 128, kk + 16);
            } else {
                #pragma unroll
                for (int n = 0; n < 8; ++n) wfn[n] = wfc[n];
            }
            float4 p0 = *(const float4*)(pw + kk), p1 = *(const float4*)(pw + kk + 4);
            float4 s0 = *(const float4*)(sw + kk), s1v = *(const float4*)(sw + kk + 4);
            pd += cu0.x*p0.x + cu0.y*p0.y + cu0.z*p0.z + cu0.w*p0.w
                + cu1.x*p1.x + cu1.y*p1.y + cu1.z*p1.z + cu1.w*p1.w;
            rd += cu0.x*s0.x + cu0.y*s0.y + cu0.z*s0.z + cu0.w*s0.w
                + cu1.x*s1v.x + cu1.y*s1v.y + cu1.z*s1v.z + cu1.w*s1v.w;
            union { unsigned u[4]; bf16x8 v; } bu;
            bu.u[0] = pack2(cu0.x, cu0.y); bu.u[1] = pack2(cu0.z, cu0.w);
            bu.u[2] = pack2(cu1.x, cu1.y); bu.u[3] = pack2(cu1.z, cu1.w);
            #pragma unroll
            for (int n = 0; n < 8; ++n)
                acc[n] = __builtin_amdgcn_mfma_f32_32x32x16_bf16(wfc[n], bu.v, acc[n], 0, 0, 0);
            cu0 = nu0; cu1 = nu1;
            #pragma unroll
            for (int n = 0; n < 8; ++n) wfc[n] = wfn[n];
        }

        pd += __shfl_xor(pd, 32);
        rd += __shfl_xor(rd, 32);
        float cjv = cj[src0];
        if (lane < 32) {
            ga[ic] = sigmoidf(pd) * cjv;
            gb[ic] = sigmoidf(rd) * cjv;
        }

        // t1 -> LDS (gelu, packed b64 chunks)
        #pragma unroll
        for (int n = 0; n < 8; ++n)
            #pragma unroll
            for (int p = 0; p < 4; ++p) {
                uint2 w;
                w.x = pack2(gelu_erf(acc[n][4*p + 0]), gelu_erf(acc[n][4*p + 1]));
                w.y = pack2(gelu_erf(acc[n][4*p + 2]), gelu_erf(acc[n][4*p + 3]));
                sttf(t_lds, row_l, n, p, kg, w);
            }
    }
    __syncthreads();

    // ================= stage 2: swapped, K=256, LDS in-place =================
    {
        f32x16 acc[8];
        #pragma unroll
        for (int n = 0; n < 8; ++n) acc[n] = (f32x16)0.0f;

        bf16x8 tfc = ldtf(t_lds, row_l, 0, kg);
        bf16x8 wfc[8];
        load_wfrags<8>(wfc, w2b, l31, 256, kg * 8);

        #pragma unroll
        for (int ks = 0; ks < 16; ++ks) {
            bf16x8 tfn = tfc, wfn[8];
            if (ks < 15) {
                tfn = ldtf(t_lds, row_l, ks + 1, kg);
                load_wfrags<8>(wfn, w2b, l31, 256, (ks + 1) * 16 + kg * 8);
            } else {
                #pragma unroll
                for (int n = 0; n < 8; ++n) wfn[n] = wfc[n];
            }
            #pragma unroll
            for (int n = 0; n < 8; ++n)
                acc[n] = __builtin_amdgcn_mfma_f32_32x32x16_bf16(wfc[n], tfc, acc[n], 0, 0, 0);
            tfc = tfn;
            #pragma unroll
            for (int n = 0; n < 8; ++n) wfc[n] = wfn[n];
        }
        __syncthreads();   // everyone done reading t1 before overwrite
        #pragma unroll
        for (int n = 0; n < 8; ++n)
            #pragma unroll
            for (int p = 0; p < 4; ++p) {
                uint2 w;
                w.x = pack2(gelu_erf(acc[n][4*p + 0]), gelu_erf(acc[n][4*p + 1]));
                w.y = pack2(gelu_erf(acc[n][4*p + 2]), gelu_erf(acc[n][4*p + 3]));
                sttf(t_lds, row_l, n, p, kg, w);
            }
    }
    __syncthreads();

    // ================= stage 3: normal, K=256, coalesced m =================
    {
        f32x16 acc[2][4];
        #pragma unroll
        for (int mi = 0; mi < 2; ++mi)
            #pragma unroll
            for (int n = 0; n < 4; ++n) acc[mi][n] = (f32x16)0.0f;

        const int rbase = (wid >> 1) * 64;        // local row base (64 edges)
        const int colh  = (wid & 1) * 128;        // column half

        bf16x8 tca = ldtf(t_lds, rbase + l31, 0, kg);
        bf16x8 tcb = ldtf(t_lds, rbase + 32 + l31, 0, kg);
        bf16x8 wfc[4];
        load_wfrags<4>(wfc, w3b, colh + l31, 256, kg * 8);

        #pragma unroll
        for (int ks = 0; ks < 16; ++ks) {
            bf16x8 tna = tca, tnb = tcb, wfn[4];
            if (ks < 15) {
                tna = ldtf(t_lds, rbase + l31, ks + 1, kg);
                tnb = ldtf(t_lds, rbase + 32 + l31, ks + 1, kg);
                load_wfrags<4>(wfn, w3b, colh + l31, 256, (ks + 1) * 16 + kg * 8);
            } else {
                #pragma unroll
                for (int n = 0; n < 4; ++n) wfn[n] = wfc[n];
            }
            #pragma unroll
            for (int n = 0; n < 4; ++n) {
                acc[0][n] = __builtin_amdgcn_mfma_f32_32x32x16_bf16(tca, wfc[n], acc[0][n], 0, 0, 0);
                acc[1][n] = __builtin_amdgcn_mfma_f32_32x32x16_bf16(tcb, wfc[n], acc[1][n], 0, 0, 0);
            }
            tca = tna; tcb = tnb;
            #pragma unroll
            for (int n = 0; n < 4; ++n) wfc[n] = wfn[n];
        }

        // epilogue: m[i] = feat[src]*ga + rf*gb (rows = sorted order, coalesced)
        #pragma unroll
        for (int mi = 0; mi < 2; ++mi) {
            #pragma unroll
            for (int r = 0; r < 16; ++r) {
                const int lrow = rbase + mi * 32 + (r & 3) + 8 * (r >> 2) + 4 * kg;
                const int gi = blk0 + lrow;
                if (gi >= E) continue;
                const int s = esrc_s[gi];
                const float gav = ga[gi], gbv = gb[gi];
                #pragma unroll
                for (int n = 0; n < 4; ++n) {
                    const int col = colh + n * 32 + l31;
                    float fv = feat[(size_t)s * 256 + col];
                    m[(size_t)gi * 256 + col] = f2bf(fv * gav + acc[mi][n][r] * gbv);
                }
            }
        }
    }
}

// ---------------- segment sum over sorted m: one wave per dst ----------------
__global__ __launch_bounds__(256) void segsum_kernel(
    const int* __restrict__ start, const unsigned short* __restrict__ m,
    unsigned short* __restrict__ h, int ND)
{
    int d = blockIdx.x * 4 + (threadIdx.x >> 6);
    if (d >= ND) return;
    int lane = threadIdx.x & 63;
    int s0 = start[d], s1 = start[d + 1];
    float a0 = 0.f, a1 = 0.f, a2 = 0.f, a3 = 0.f;
    for (int i = s0; i < s1; ++i) {
        ushort4 v = *(const ushort4*)(m + (size_t)i * 256 + lane * 4);
        a0 += bf2f(v.x); a1 += bf2f(v.y); a2 += bf2f(v.z); a3 += bf2f(v.w);
    }
    ushort4 o; o.x = f2bf(a0); o.y = f2bf(a1); o.z = f2bf(a2); o.w = f2bf(a3);
    *(ushort4*)(h + (size_t)d * 256 + lane * 4) = o;
}

// ---------------- g4: out = (h @ lin_w^T)*ci + b ----------------
__global__ __launch_bounds__(256, 2) void g4_kernel(
    const unsigned short* __restrict__ Ab, const unsigned short* __restrict__ Wb,
    float* __restrict__ outf, const float* __restrict__ ci,
    const float* __restrict__ bias, int M)
{
    const int lane = threadIdx.x & 63;
    const int wid  = threadIdx.x >> 6;
    const int l31  = lane & 31;
    const int kg   = lane >> 5;
    const int colh = (wid & 1) * 128;
    const int wbase = blockIdx.x * 128 + (wid >> 1) * 64;
    const int r0 = wbase + l31, r1 = wbase + 32 + l31;
    const int ar0 = (r0 < M) ? r0 : (M - 1);
    const int ar1 = (r1 < M) ? r1 : (M - 1);

    f32x16 acc[2][4];
    #pragma unroll
    for (int mi = 0; mi < 2; ++mi)
        #pragma unroll
        for (int n = 0; n < 4; ++n) acc[mi][n] = (f32x16)0.0f;

    for (int k0 = 0; k0 < 256; k0 += 16) {
        const int kk = k0 + kg * 8;
        bf16x8 a0 = *(const bf16x8*)(Ab + (size_t)ar0 * 256 + kk);
        bf16x8 a1 = *(const bf16x8*)(Ab + (size_t)ar1 * 256 + kk);
        const unsigned short* wbp = Wb + (size_t)(colh + l31) * 256 + kk;
        #pragma unroll
        for (int n = 0; n < 4; ++n) {
            bf16x8 b = *(const bf16x8*)(wbp + (size_t)(n * 32) * 256);
            acc[0][n] = __builtin_amdgcn_mfma_f32_32x32x16_bf16(a0, b, acc[0][n], 0, 0, 0);
            acc[1][n] = __builtin_amdgcn_mfma_f32_32x32x16_bf16(a1, b, acc[1][n], 0, 0, 0);
        }
    }
    #pragma unroll
    for (int mi = 0; mi < 2; ++mi) {
        #pragma unroll
        for (int r = 0; r < 16; ++r) {
            const int gr = wbase + mi * 32 + (r & 3) + 8 * (r >> 2) + 4 * kg;
            if (gr >= M) continue;
            float civ = ci[gr];
            #pragma unroll
            for (int n = 0; n < 4; ++n) {
                int col = colh + n * 32 + l31;
                outf[(size_t)gr * 256 + col] = acc[mi][n][r] * civ + bias[col];
            }
        }
    }
}

extern "C" void kernel_launch(void* const* d_in, const int* in_sizes, int n_in,
                              void* d_out, int out_size, void* d_ws, size_t ws_size,
                              hipStream_t stream) {
    const float* feat = (const float*)d_in[0];
    const float* cj   = (const float*)d_in[1];
    const float* ci   = (const float*)d_in[2];
    const int*   esrc = (const int*)d_in[3];
    const int*   edst = (const int*)d_in[4];
    const int*   rid  = (const int*)d_in[5];
    const float* remb = (const float*)d_in[6];
    const float* pw   = (const float*)d_in[7];
    const float* sw   = (const float*)d_in[8];
    const float* rw1  = (const float*)d_in[9];
    const float* rw2  = (const float*)d_in[10];
    const float* rw3  = (const float*)d_in[11];
    const float* lw   = (const float*)d_in[12];
    const float* lb   = (const float*)d_in[13];
    float* out = (float*)d_out;

    const int E  = in_sizes[3];   // 300000
    const int ND = in_sizes[2];   // 100000

    // workspace carve-up
    char* ws = (char*)d_ws;
    float* ga = (float*)ws;                               // E f32
    float* gb = ga + E;                                   // E f32
    unsigned short* m   = (unsigned short*)(gb + E);      // E*256 bf16
    unsigned short* h   = m + (size_t)E * 256;            // ND*256 bf16
    unsigned short* w1b = h + (size_t)ND * 256;           // 256*128
    unsigned short* w2b = w1b + 256 * 128;                // 256*256
    unsigned short* w3b = w2b + 256 * 256;
    unsigned short* lwb = w3b + 256 * 256;
    int* cnt    = (int*)(lwb + 256 * 256);                // ND
    int* start  = cnt + ND;                               // ND+1
    int* bsum   = start + ND + 1;                         // 128
    int* within = bsum + 128;                             // E
    int* eidx   = within + E;                             // E
    int* rid_s  = eidx + E;                               // E
    int* esrc_s = rid_s + E;                              // E

    const int NB = (ND + 1023) / 1024;

    hipMemsetAsync(cnt, 0, (size_t)ND * sizeof(int), stream);
    prep_weights<<<256, 256, 0, stream>>>(rw1, rw2, rw3, lw, w1b, w2b, w3b, lwb);

    // CSR build + sorted-edge gathers
    hist_kernel<<<(E + 255) / 256, 256, 0, stream>>>(edst, cnt, within, E);
    scan_block<<<NB, 1024, 0, stream>>>(cnt, start, bsum, ND);
    scan_bsum<<<1, 64, 0, stream>>>(bsum, NB);
    add_offsets<<<NB, 1024, 0, stream>>>(start, bsum, ND, E);
    build_eidx<<<(E + 255) / 256, 256, 0, stream>>>(edst, within, start, eidx, E);
    gather_sorted<<<(E + 255) / 256, 256, 0, stream>>>(eidx, rid, esrc, rid_s, esrc_s, E);

    // fused g1+g2+g3 (t staged in LDS)
    fused_edge<<<(E + 127) / 128, 256, 0, stream>>>(
        remb, rid_s, esrc_s, w1b, w2b, w3b, pw, sw, cj, feat, ga, gb, m, E);

    // segsum over contiguous sorted rows
    segsum_kernel<<<(ND + 3) / 4, 256, 0, stream>>>(start, m, h, ND);

    // g4
    g4_kernel<<<(ND + 127) / 128, 256, 0, stream>>>(h, lwb, out, ci, lb, ND);
}

// Round 6
// 579.482 us; speedup vs baseline: 1.7670x; 1.2276x over previous
//
#include <hip/hip_runtime.h>
#include <math.h>
#include <stdint.h>

// Fused pipeline (E=300000, ND=100000, FEAT=256, RDIM=128):
//   prep:   weights -> bf16 in FRAGMENT ORDER (coalesced MFMA B-operand loads)
//   CSR:    hist, scan, scan_bsum, add_offsets, build_eidx (sort edges by dst)
//   gather: rid_s/esrc_s = rid/esrc[eidx]
//   fused (512 thr = 8 waves, 128 edges/block, t staged in 64KB LDS):
//     s1 (swapped mfma, K=128): wave (g=w>>1, f=w&1): edges g*32.., feats f*128..
//         t1 = gelu(W1 @ remb_row) + pa/ra dots -> ga/gb (f==0 waves write)
//     s2 (swapped, K=256): same split, t2 = gelu(W2 @ t1) (LDS in-place)
//     s3 (normal, K=256): wave (rg=w>>1, f=w&1): rows rg*32.., cols f*128..
//         m = feat[src]*ga + (t2 @ W3^T)*gb  (coalesced, dst-sorted)
//   segsum: h[d] = sum of contiguous m rows (CSR ranges)
//   g4:     out = (h @ lin_w^T)*ci + b
// mfma_f32_32x32x16_bf16 layouts (HW-validated R2-R5):
//   A: row=lane&31, k=8*(lane>>5)+j ; B: col=lane&31, same k
//   D: col=lane&31, row=(reg&3)+8*(reg>>2)+4*(lane>>5)
// Weight fragment table: wS[(((ks*8 + n)*2 + kg)*32 + l31)*8 + j] = W[n*32+l31][ks*16+kg*8+j]
// LDS t: row=local edge, 512B/row, 16B-slot swizzle slot^=(row&7) (both sides).

typedef short bf16x8 __attribute__((ext_vector_type(8)));
typedef float f32x16 __attribute__((ext_vector_type(16)));

__device__ __forceinline__ float bf2f(unsigned short v) {
    union { unsigned int u; float f; } x; x.u = ((unsigned int)v) << 16; return x.f;
}
__device__ __forceinline__ unsigned short f2bf(float f) {
    union { float f; unsigned int u; } x; x.f = f;
    unsigned int u = x.u;
    return (unsigned short)((u + 0x7FFFu + ((u >> 16) & 1u)) >> 16);
}
__device__ __forceinline__ unsigned pack2(float lo, float hi) {
    return (unsigned)f2bf(lo) | ((unsigned)f2bf(hi) << 16);
}
__device__ __forceinline__ float gelu_erf(float x) {
    return 0.5f * x * (1.0f + erff(x * 0.70710678118654752f));
}
__device__ __forceinline__ float sigmoidf(float x) {
    return 1.0f / (1.0f + expf(-x));
}

// weights -> bf16 fragment-ordered tables
__global__ __launch_bounds__(256) void prep_weights(
    const float* __restrict__ rw1, const float* __restrict__ rw2,
    const float* __restrict__ rw3, const float* __restrict__ lw,
    unsigned short* __restrict__ w1s, unsigned short* __restrict__ w2s,
    unsigned short* __restrict__ w3s, unsigned short* __restrict__ lws)
{
    int i = blockIdx.x * blockDim.x + threadIdx.x;
    int j  = i & 7;
    int l  = (i >> 3) & 31;
    int kgg = (i >> 8) & 1;
    int n  = (i >> 9) & 7;
    int ks = i >> 12;
    if (i < 32768) {   // K=128: ks 0..7
        w1s[i] = f2bf(rw1[(n * 32 + l) * 128 + ks * 16 + kgg * 8 + j]);
    }
    if (i < 65536) {   // K=256: ks 0..15
        int row = n * 32 + l, k = ks * 16 + kgg * 8 + j;
        w2s[i] = f2bf(rw2[(size_t)row * 256 + k]);
        w3s[i] = f2bf(rw3[(size_t)row * 256 + k]);
        lws[i] = f2bf(lw[(size_t)row * 256 + k]);
    }
}

// fragment load from pre-swizzled table (contiguous, coalesced)
__device__ __forceinline__ bf16x8 ldw(const unsigned short* __restrict__ W,
                                      int ks, int nglob, int kg, int l31) {
    return *(const bf16x8*)(W + (((((ks * 8 + nglob) * 2) + kg) * 32 + l31) << 3));
}

// ---------------- CSR build ----------------
__global__ __launch_bounds__(256) void hist_kernel(
    const int* __restrict__ edst, int* __restrict__ cnt,
    int* __restrict__ within, int E)
{
    int e = blockIdx.x * blockDim.x + threadIdx.x;
    if (e < E) within[e] = atomicAdd(&cnt[edst[e]], 1);
}

__global__ __launch_bounds__(1024) void scan_block(
    const int* __restrict__ cnt, int* __restrict__ start,
    int* __restrict__ bsum, int n)
{
    __shared__ int s[1024];
    int gid = blockIdx.x * 1024 + threadIdx.x;
    int v = (gid < n) ? cnt[gid] : 0;
    s[threadIdx.x] = v;
    __syncthreads();
    #pragma unroll
    for (int off = 1; off < 1024; off <<= 1) {
        int t = (threadIdx.x >= off) ? s[threadIdx.x - off] : 0;
        __syncthreads();
        if (threadIdx.x >= off) s[threadIdx.x] += t;
        __syncthreads();
    }
    if (gid < n) start[gid] = s[threadIdx.x] - v;   // exclusive
    if (threadIdx.x == 1023) bsum[blockIdx.x] = s[1023];
}

__global__ void scan_bsum(int* __restrict__ bsum, int nb) {
    if (threadIdx.x == 0 && blockIdx.x == 0) {
        int acc = 0;
        for (int i = 0; i < nb; ++i) { int v = bsum[i]; bsum[i] = acc; acc += v; }
    }
}

__global__ __launch_bounds__(1024) void add_offsets(
    int* __restrict__ start, const int* __restrict__ bsum, int n, int E)
{
    int gid = blockIdx.x * 1024 + threadIdx.x;
    if (gid < n) start[gid] += bsum[gid >> 10];
    if (gid == 0) start[n] = E;
}

__global__ __launch_bounds__(256) void build_eidx(
    const int* __restrict__ edst, const int* __restrict__ within,
    const int* __restrict__ start, int* __restrict__ eidx, int E)
{
    int e = blockIdx.x * blockDim.x + threadIdx.x;
    if (e < E) eidx[start[edst[e]] + within[e]] = e;
}

__global__ __launch_bounds__(256) void gather_sorted(
    const int* __restrict__ eidx, const int* __restrict__ rid,
    const int* __restrict__ esrc, int* __restrict__ rid_s,
    int* __restrict__ esrc_s, int E)
{
    int t = blockIdx.x * blockDim.x + threadIdx.x;
    if (t < E) { int e = eidx[t]; rid_s[t] = rid[e]; esrc_s[t] = esrc[e]; }
}

// ---------------- LDS t helpers (16B-slot XOR swizzle) ----------------
__device__ __forceinline__ bf16x8 ldtf(const unsigned short* t_lds, int row, int ks, int kg) {
    int slot = (ks * 2 + kg) ^ (row & 7);
    return *(const bf16x8*)((const char*)t_lds + row * 512 + slot * 16);
}
__device__ __forceinline__ void sttf(unsigned short* t_lds, int row, int nn, int p, int kg, uint2 w) {
    int slot = (nn * 4 + p) ^ (row & 7);
    *(uint2*)((char*)t_lds + row * 512 + slot * 16 + kg * 8) = w;
}

// ---------------- fused g1+g2+g3 ----------------
__global__ __launch_bounds__(512, 4) void fused_edge(
    const float* __restrict__ remb, const int* __restrict__ rid_s,
    const int* __restrict__ esrc_s,
    const unsigned short* __restrict__ w1s, const unsigned short* __restrict__ w2s,
    const unsigned short* __restrict__ w3s,
    const float* __restrict__ pw, const float* __restrict__ sw,
    const float* __restrict__ cj, const float* __restrict__ feat,
    float* __restrict__ ga, float* __restrict__ gb,
    unsigned short* __restrict__ m, int E)
{
    __shared__ __align__(16) unsigned short t_lds[128 * 256];   // 64 KB

    const int lane = threadIdx.x & 63;
    const int wid  = threadIdx.x >> 6;       // 0..7
    const int l31  = lane & 31;
    const int kg   = lane >> 5;              // 0..1
    const int g    = wid >> 1;               // edge group (s1/s2) / row group (s3)
    const int f    = wid & 1;                // feature half
    const int blk0 = blockIdx.x * 128;
    const int i    = blk0 + g * 32 + l31;    // lane's edge (s1/s2)
    const int ic   = (i < E) ? i : (E - 1);
    const int rid0 = rid_s[ic];
    const int src0 = esrc_s[ic];
    const int row_l = g * 32 + l31;          // local LDS row

    // ================= stage 1: swapped, K=128, fused pa/ra =================
    {
        f32x16 acc[4];
        #pragma unroll
        for (int n = 0; n < 4; ++n) acc[n] = (f32x16)0.0f;
        float pd = 0.f, rd = 0.f;
        const float* rbase = remb + (size_t)rid0 * 128;

        #pragma unroll
        for (int ks = 0; ks < 8; ++ks) {
            const int kk = ks * 16 + kg * 8;
            float4 u0 = *(const float4*)(rbase + kk);
            float4 u1 = *(const float4*)(rbase + kk + 4);
            float4 p0 = *(const float4*)(pw + kk), p1 = *(const float4*)(pw + kk + 4);
            float4 s0 = *(const float4*)(sw + kk), s1v = *(const float4*)(sw + kk + 4);
            pd += u0.x*p0.x + u0.y*p0.y + u0.z*p0.z + u0.w*p0.w
                + u1.x*p1.x + u1.y*p1.y + u1.z*p1.z + u1.w*p1.w;
            rd += u0.x*s0.x + u0.y*s0.y + u0.z*s0.z + u0.w*s0.w
                + u1.x*s1v.x + u1.y*s1v.y + u1.z*s1v.z + u1.w*s1v.w;
            union { unsigned u[4]; bf16x8 v; } bu;
            bu.u[0] = pack2(u0.x, u0.y); bu.u[1] = pack2(u0.z, u0.w);
            bu.u[2] = pack2(u1.x, u1.y); bu.u[3] = pack2(u1.z, u1.w);
            #pragma unroll
            for (int n = 0; n < 4; ++n) {
                bf16x8 wf = ldw(w1s, ks, f * 4 + n, kg, l31);
                acc[n] = __builtin_amdgcn_mfma_f32_32x32x16_bf16(wf, bu.v, acc[n], 0, 0, 0);
            }
        }

        pd += __shfl_xor(pd, 32);
        rd += __shfl_xor(rd, 32);
        if (f == 0 && lane < 32 && i < E) {
            float cjv = cj[src0];
            ga[i] = sigmoidf(pd) * cjv;
            gb[i] = sigmoidf(rd) * cjv;
        }

        // t1 -> LDS (gelu, packed b64 chunks)
        #pragma unroll
        for (int n = 0; n < 4; ++n)
            #pragma unroll
            for (int p = 0; p < 4; ++p) {
                uint2 w;
                w.x = pack2(gelu_erf(acc[n][4*p + 0]), gelu_erf(acc[n][4*p + 1]));
                w.y = pack2(gelu_erf(acc[n][4*p + 2]), gelu_erf(acc[n][4*p + 3]));
                sttf(t_lds, row_l, f * 4 + n, p, kg, w);
            }
    }
    __syncthreads();

    // ================= stage 2: swapped, K=256, LDS in-place =================
    {
        f32x16 acc[4];
        #pragma unroll
        for (int n = 0; n < 4; ++n) acc[n] = (f32x16)0.0f;

        #pragma unroll
        for (int ks = 0; ks < 16; ++ks) {
            bf16x8 tf = ldtf(t_lds, row_l, ks, kg);
            #pragma unroll
            for (int n = 0; n < 4; ++n) {
                bf16x8 wf = ldw(w2s, ks, f * 4 + n, kg, l31);
                acc[n] = __builtin_amdgcn_mfma_f32_32x32x16_bf16(wf, tf, acc[n], 0, 0, 0);
            }
        }
        __syncthreads();   // everyone done reading t1 before overwrite
        #pragma unroll
        for (int n = 0; n < 4; ++n)
            #pragma unroll
            for (int p = 0; p < 4; ++p) {
                uint2 w;
                w.x = pack2(gelu_erf(acc[n][4*p + 0]), gelu_erf(acc[n][4*p + 1]));
                w.y = pack2(gelu_erf(acc[n][4*p + 2]), gelu_erf(acc[n][4*p + 3]));
                sttf(t_lds, row_l, f * 4 + n, p, kg, w);
            }
    }
    __syncthreads();

    // ================= stage 3: normal, K=256, coalesced m =================
    {
        f32x16 acc[4];
        #pragma unroll
        for (int n = 0; n < 4; ++n) acc[n] = (f32x16)0.0f;

        const int rrow = g * 32 + l31;     // A-frag local edge row

        #pragma unroll
        for (int ks = 0; ks < 16; ++ks) {
            bf16x8 tf = ldtf(t_lds, rrow, ks, kg);
            #pragma unroll
            for (int n = 0; n < 4; ++n) {
                bf16x8 wf = ldw(w3s, ks, f * 4 + n, kg, l31);
                acc[n] = __builtin_amdgcn_mfma_f32_32x32x16_bf16(tf, wf, acc[n], 0, 0, 0);
            }
        }

        // epilogue: m[i] = feat[src]*ga + rf*gb (rows = sorted order, coalesced)
        #pragma unroll
        for (int r = 0; r < 16; ++r) {
            const int lrow = g * 32 + (r & 3) + 8 * (r >> 2) + 4 * kg;
            const int gi = blk0 + lrow;
            if (gi >= E) continue;
            const int s = esrc_s[gi];
            const float gav = ga[gi], gbv = gb[gi];
            #pragma unroll
            for (int n = 0; n < 4; ++n) {
                const int col = f * 128 + n * 32 + l31;
                float fv = feat[(size_t)s * 256 + col];
                m[(size_t)gi * 256 + col] = f2bf(fv * gav + acc[n][r] * gbv);
            }
        }
    }
}

// ---------------- segment sum over sorted m: one wave per dst ----------------
__global__ __launch_bounds__(256) void segsum_kernel(
    const int* __restrict__ start, const unsigned short* __restrict__ m,
    unsigned short* __restrict__ h, int ND)
{
    int d = blockIdx.x * 4 + (threadIdx.x >> 6);
    if (d >= ND) return;
    int lane = threadIdx.x & 63;
    int s0 = start[d], s1 = start[d + 1];
    float a0 = 0.f, a1 = 0.f, a2 = 0.f, a3 = 0.f;
    for (int i = s0; i < s1; ++i) {
        ushort4 v = *(const ushort4*)(m + (size_t)i * 256 + lane * 4);
        a0 += bf2f(v.x); a1 += bf2f(v.y); a2 += bf2f(v.z); a3 += bf2f(v.w);
    }
    ushort4 o; o.x = f2bf(a0); o.y = f2bf(a1); o.z = f2bf(a2); o.w = f2bf(a3);
    *(ushort4*)(h + (size_t)d * 256 + lane * 4) = o;
}

// ---------------- g4: out = (h @ lin_w^T)*ci + b ----------------
__global__ __launch_bounds__(256, 2) void g4_kernel(
    const unsigned short* __restrict__ Ab, const unsigned short* __restrict__ lws,
    float* __restrict__ outf, const float* __restrict__ ci,
    const float* __restrict__ bias, int M)
{
    const int lane = threadIdx.x & 63;
    const int wid  = threadIdx.x >> 6;
    const int l31  = lane & 31;
    const int kg   = lane >> 5;
    const int f    = wid & 1;                 // column half
    const int wbase = blockIdx.x * 128 + (wid >> 1) * 64;
    const int r0 = wbase + l31, r1 = wbase + 32 + l31;
    const int ar0 = (r0 < M) ? r0 : (M - 1);
    const int ar1 = (r1 < M) ? r1 : (M - 1);

    f32x16 acc[2][4];
    #pragma unroll
    for (int mi = 0; mi < 2; ++mi)
        #pragma unroll
        for (int n = 0; n < 4; ++n) acc[mi][n] = (f32x16)0.0f;

    #pragma unroll
    for (int ks = 0; ks < 16; ++ks) {
        const int kk = ks * 16 + kg * 8;
        bf16x8 a0 = *(const bf16x8*)(Ab + (size_t)ar0 * 256 + kk);
        bf16x8 a1 = *(const bf16x8*)(Ab + (size_t)ar1 * 256 + kk);
        #pragma unroll
        for (int n = 0; n < 4; ++n) {
            bf16x8 b = ldw(lws, ks, f * 4 + n, kg, l31);
            acc[0][n] = __builtin_amdgcn_mfma_f32_32x32x16_bf16(a0, b, acc[0][n], 0, 0, 0);
            acc[1][n] = __builtin_amdgcn_mfma_f32_32x32x16_bf16(a1, b, acc[1][n], 0, 0, 0);
        }
    }
    #pragma unroll
    for (int mi = 0; mi < 2; ++mi) {
        #pragma unroll
        for (int r = 0; r < 16; ++r) {
            const int gr = wbase + mi * 32 + (r & 3) + 8 * (r >> 2) + 4 * kg;
            if (gr >= M) continue;
            float civ = ci[gr];
            #pragma unroll
            for (int n = 0; n < 4; ++n) {
                int col = f * 128 + n * 32 + l31;
                outf[(size_t)gr * 256 + col] = acc[mi][n][r] * civ + bias[col];
            }
        }
    }
}

extern "C" void kernel_launch(void* const* d_in, const int* in_sizes, int n_in,
                              void* d_out, int out_size, void* d_ws, size_t ws_size,
                              hipStream_t stream) {
    const float* feat = (const float*)d_in[0];
    const float* cj   = (const float*)d_in[1];
    const float* ci   = (const float*)d_in[2];
    const int*   esrc = (const int*)d_in[3];
    const int*   edst = (const int*)d_in[4];
    const int*   rid  = (const int*)d_in[5];
    const float* remb = (const float*)d_in[6];
    const float* pw   = (const float*)d_in[7];
    const float* sw   = (const float*)d_in[8];
    const float* rw1  = (const float*)d_in[9];
    const float* rw2  = (const float*)d_in[10];
    const float* rw3  = (const float*)d_in[11];
    const float* lw   = (const float*)d_in[12];
    const float* lb   = (const float*)d_in[13];
    float* out = (float*)d_out;

    const int E  = in_sizes[3];   // 300000
    const int ND = in_sizes[2];   // 100000

    // workspace carve-up
    char* ws = (char*)d_ws;
    float* ga = (float*)ws;                               // E f32
    float* gb = ga + E;                                   // E f32
    unsigned short* m   = (unsigned short*)(gb + E);      // E*256 bf16
    unsigned short* h   = m + (size_t)E * 256;            // ND*256 bf16
    unsigned short* w1s = h + (size_t)ND * 256;           // 32768
    unsigned short* w2s = w1s + 32768;                    // 65536
    unsigned short* w3s = w2s + 65536;                    // 65536
    unsigned short* lws = w3s + 65536;                    // 65536
    int* cnt    = (int*)(lws + 65536);                    // ND
    int* start  = cnt + ND;                               // ND+1
    int* bsum   = start + ND + 1;                         // 128
    int* within = bsum + 128;                             // E
    int* eidx   = within + E;                             // E
    int* rid_s  = eidx + E;                               // E
    int* esrc_s = rid_s + E;                              // E

    const int NB = (ND + 1023) / 1024;

    hipMemsetAsync(cnt, 0, (size_t)ND * sizeof(int), stream);
    prep_weights<<<256, 256, 0, stream>>>(rw1, rw2, rw3, lw, w1s, w2s, w3s, lws);

    // CSR build + sorted-edge gathers
    hist_kernel<<<(E + 255) / 256, 256, 0, stream>>>(edst, cnt, within, E);
    scan_block<<<NB, 1024, 0, stream>>>(cnt, start, bsum, ND);
    scan_bsum<<<1, 64, 0, stream>>>(bsum, NB);
    add_offsets<<<NB, 1024, 0, stream>>>(start, bsum, ND, E);
    build_eidx<<<(E + 255) / 256, 256, 0, stream>>>(edst, within, start, eidx, E);
    gather_sorted<<<(E + 255) / 256, 256, 0, stream>>>(eidx, rid, esrc, rid_s, esrc_s, E);

    // fused g1+g2+g3 (8 waves, t staged in LDS)
    fused_edge<<<(E + 127) / 128, 512, 0, stream>>>(
        remb, rid_s, esrc_s, w1s, w2s, w3s, pw, sw, cj, feat, ga, gb, m, E);

    // segsum over contiguous sorted rows
    segsum_kernel<<<(ND + 3) / 4, 256, 0, stream>>>(start, m, h, ND);

    // g4
    g4_kernel<<<(ND + 127) / 128, 256, 0, stream>>>(h, lws, out, ci, lb, ND);
}

// Round 7
// 527.220 us; speedup vs baseline: 1.9421x; 1.0991x over previous
//
#include <hip/hip_runtime.h>
#include <math.h>
#include <stdint.h>

// Fused pipeline (E=300000, ND=100000, FEAT=256, RDIM=128):
//   prep:   weights -> bf16 fragment-ordered tables (lws additionally k-permuted)
//   CSR:    hist, scan, scan_bsum, add_offsets, build_eidx (sort edges by dst)
//   gather: rid_s/esrc_s = rid/esrc[eidx]
//   fused (512 thr = 8 waves (g=wid>>2 edge-group, f=wid&3 feat-quarter),
//          64 edges/block, 32KB LDS, launch_bounds(512,6) -> 3 blocks/CU):
//     s1 (swapped mfma, K=128): t1 = gelu(W1 @ remb_row) + pa/ra dots (gva/gvb in regs)
//     s2 (swapped, K=256):      t2 = gelu(W2 @ t1)  (LDS in-place)
//     s3 (normal, K=256):       feat prefetched to regs BEFORE k-loop;
//         m = feat[src]*gva + (t2 @ W3^T)*gvb, stored col-PERMUTED as packed b32:
//         stored[f*64 + l31*2 + n] = true col f*64 + n*32 + l31
//   segsum: h[d] = sum of contiguous m rows (element-wise, permuted space)
//   g4:     out = (h @ lin_w^T)*ci + b   (perm inverted inside lws prep)
// mfma_f32_32x32x16_bf16 layouts (HW-validated R2-R6):
//   A: row=lane&31, k=8*(lane>>5)+j ; B: col=lane&31, same k
//   D: col=lane&31, row=(reg&3)+8*(reg>>2)+4*(lane>>5)
// LDS t: row=local edge (64), 512B/row, 16B-slot swizzle slot^=(row&7) (both sides).

typedef short bf16x8 __attribute__((ext_vector_type(8)));
typedef float f32x16 __attribute__((ext_vector_type(16)));

__device__ __forceinline__ float bf2f(unsigned short v) {
    union { unsigned int u; float f; } x; x.u = ((unsigned int)v) << 16; return x.f;
}
__device__ __forceinline__ unsigned short f2bf(float f) {
    union { float f; unsigned int u; } x; x.f = f;
    unsigned int u = x.u;
    return (unsigned short)((u + 0x7FFFu + ((u >> 16) & 1u)) >> 16);
}
__device__ __forceinline__ unsigned pack2(float lo, float hi) {
    return (unsigned)f2bf(lo) | ((unsigned)f2bf(hi) << 16);
}
__device__ __forceinline__ float gelu_erf(float x) {
    return 0.5f * x * (1.0f + erff(x * 0.70710678118654752f));
}
__device__ __forceinline__ float sigmoidf(float x) {
    return 1.0f / (1.0f + expf(-x));
}

// weights -> bf16 fragment-ordered tables; lws gets the m/h column perm baked in
__global__ __launch_bounds__(256) void prep_weights(
    const float* __restrict__ rw1, const float* __restrict__ rw2,
    const float* __restrict__ rw3, const float* __restrict__ lw,
    unsigned short* __restrict__ w1s, unsigned short* __restrict__ w2s,
    unsigned short* __restrict__ w3s, unsigned short* __restrict__ lws)
{
    int i = blockIdx.x * blockDim.x + threadIdx.x;
    int j   = i & 7;
    int l   = (i >> 3) & 31;
    int kgg = (i >> 8) & 1;
    int n2  = (i >> 9) & 7;
    int ks  = i >> 12;
    if (i < 32768) {   // K=128: ks 0..7
        w1s[i] = f2bf(rw1[(n2 * 32 + l) * 128 + ks * 16 + kgg * 8 + j]);
    }
    if (i < 65536) {   // K=256: ks 0..15
        int row = n2 * 32 + l, k = ks * 16 + kgg * 8 + j;
        w2s[i] = f2bf(rw2[(size_t)row * 256 + k]);
        w3s[i] = f2bf(rw3[(size_t)row * 256 + k]);
        // stored pos k holds true col: (k & ~63) + (k&1)*32 + ((k&63)>>1)
        int ok = (k & 192) | ((k & 1) << 5) | ((k & 63) >> 1);
        lws[i] = f2bf(lw[(size_t)row * 256 + ok]);
    }
}

// fragment load from pre-swizzled table (contiguous, coalesced)
__device__ __forceinline__ bf16x8 ldw(const unsigned short* __restrict__ W,
                                      int ks, int nglob, int kg, int l31) {
    return *(const bf16x8*)(W + (((((ks * 8 + nglob) * 2) + kg) * 32 + l31) << 3));
}

// ---------------- CSR build ----------------
__global__ __launch_bounds__(256) void hist_kernel(
    const int* __restrict__ edst, int* __restrict__ cnt,
    int* __restrict__ within, int E)
{
    int e = blockIdx.x * blockDim.x + threadIdx.x;
    if (e < E) within[e] = atomicAdd(&cnt[edst[e]], 1);
}

__global__ __launch_bounds__(1024) void scan_block(
    const int* __restrict__ cnt, int* __restrict__ start,
    int* __restrict__ bsum, int n)
{
    __shared__ int s[1024];
    int gid = blockIdx.x * 1024 + threadIdx.x;
    int v = (gid < n) ? cnt[gid] : 0;
    s[threadIdx.x] = v;
    __syncthreads();
    #pragma unroll
    for (int off = 1; off < 1024; off <<= 1) {
        int t = (threadIdx.x >= off) ? s[threadIdx.x - off] : 0;
        __syncthreads();
        if (threadIdx.x >= off) s[threadIdx.x] += t;
        __syncthreads();
    }
    if (gid < n) start[gid] = s[threadIdx.x] - v;   // exclusive
    if (threadIdx.x == 1023) bsum[blockIdx.x] = s[1023];
}

__global__ void scan_bsum(int* __restrict__ bsum, int nb) {
    if (threadIdx.x == 0 && blockIdx.x == 0) {
        int acc = 0;
        for (int i = 0; i < nb; ++i) { int v = bsum[i]; bsum[i] = acc; acc += v; }
    }
}

__global__ __launch_bounds__(1024) void add_offsets(
    int* __restrict__ start, const int* __restrict__ bsum, int n, int E)
{
    int gid = blockIdx.x * 1024 + threadIdx.x;
    if (gid < n) start[gid] += bsum[gid >> 10];
    if (gid == 0) start[n] = E;
}

__global__ __launch_bounds__(256) void build_eidx(
    const int* __restrict__ edst, const int* __restrict__ within,
    const int* __restrict__ start, int* __restrict__ eidx, int E)
{
    int e = blockIdx.x * blockDim.x + threadIdx.x;
    if (e < E) eidx[start[edst[e]] + within[e]] = e;
}

__global__ __launch_bounds__(256) void gather_sorted(
    const int* __restrict__ eidx, const int* __restrict__ rid,
    const int* __restrict__ esrc, int* __restrict__ rid_s,
    int* __restrict__ esrc_s, int E)
{
    int t = blockIdx.x * blockDim.x + threadIdx.x;
    if (t < E) { int e = eidx[t]; rid_s[t] = rid[e]; esrc_s[t] = esrc[e]; }
}

// ---------------- LDS t helpers (16B-slot XOR swizzle) ----------------
__device__ __forceinline__ bf16x8 ldtf(const unsigned short* t_lds, int row, int ks, int kg) {
    int slot = (ks * 2 + kg) ^ (row & 7);
    return *(const bf16x8*)((const char*)t_lds + row * 512 + slot * 16);
}
__device__ __forceinline__ void sttf(unsigned short* t_lds, int row, int nn, int p, int kg, uint2 w) {
    int slot = (nn * 4 + p) ^ (row & 7);
    *(uint2*)((char*)t_lds + row * 512 + slot * 16 + kg * 8) = w;
}

// ---------------- fused g1+g2+g3 ----------------
__global__ __launch_bounds__(512, 6) void fused_edge(
    const float* __restrict__ remb, const int* __restrict__ rid_s,
    const int* __restrict__ esrc_s,
    const unsigned short* __restrict__ w1s, const unsigned short* __restrict__ w2s,
    const unsigned short* __restrict__ w3s,
    const float* __restrict__ pw, const float* __restrict__ sw,
    const float* __restrict__ cj, const float* __restrict__ feat,
    unsigned short* __restrict__ m, int E)
{
    __shared__ __align__(16) unsigned short t_lds[64 * 256];   // 32 KB

    const int lane = threadIdx.x & 63;
    const int wid  = threadIdx.x >> 6;       // 0..7
    const int l31  = lane & 31;
    const int kg   = lane >> 5;              // 0..1
    const int g    = wid >> 2;               // edge group (32 edges)
    const int f    = wid & 3;                // feature quarter (64 cols)
    const int blk0 = blockIdx.x * 64;
    const int i    = blk0 + g * 32 + l31;    // lane's edge
    const int ic   = (i < E) ? i : (E - 1);
    const int rid0 = rid_s[ic];
    const int src0 = esrc_s[ic];
    const int row_l = g * 32 + l31;          // local LDS row

    float gva, gvb;

    // ================= stage 1: swapped, K=128, fused pa/ra =================
    {
        f32x16 acc[2];
        acc[0] = (f32x16)0.0f; acc[1] = (f32x16)0.0f;
        float pd = 0.f, rd = 0.f;
        const float* rbase = remb + (size_t)rid0 * 128;

        #pragma unroll
        for (int ks = 0; ks < 8; ++ks) {
            const int kk = ks * 16 + kg * 8;
            float4 u0 = *(const float4*)(rbase + kk);
            float4 u1 = *(const float4*)(rbase + kk + 4);
            float4 p0 = *(const float4*)(pw + kk), p1 = *(const float4*)(pw + kk + 4);
            float4 s0 = *(const float4*)(sw + kk), s1v = *(const float4*)(sw + kk + 4);
            pd += u0.x*p0.x + u0.y*p0.y + u0.z*p0.z + u0.w*p0.w
                + u1.x*p1.x + u1.y*p1.y + u1.z*p1.z + u1.w*p1.w;
            rd += u0.x*s0.x + u0.y*s0.y + u0.z*s0.z + u0.w*s0.w
                + u1.x*s1v.x + u1.y*s1v.y + u1.z*s1v.z + u1.w*s1v.w;
            union { unsigned u[4]; bf16x8 v; } bu;
            bu.u[0] = pack2(u0.x, u0.y); bu.u[1] = pack2(u0.z, u0.w);
            bu.u[2] = pack2(u1.x, u1.y); bu.u[3] = pack2(u1.z, u1.w);
            #pragma unroll
            for (int n = 0; n < 2; ++n) {
                bf16x8 wf = ldw(w1s, ks, f * 2 + n, kg, l31);
                acc[n] = __builtin_amdgcn_mfma_f32_32x32x16_bf16(wf, bu.v, acc[n], 0, 0, 0);
            }
        }

        pd += __shfl_xor(pd, 32);
        rd += __shfl_xor(rd, 32);
        float cjv = cj[src0];
        gva = sigmoidf(pd) * cjv;
        gvb = sigmoidf(rd) * cjv;

        #pragma unroll
        for (int n = 0; n < 2; ++n)
            #pragma unroll
            for (int p = 0; p < 4; ++p) {
                uint2 w;
                w.x = pack2(gelu_erf(acc[n][4*p + 0]), gelu_erf(acc[n][4*p + 1]));
                w.y = pack2(gelu_erf(acc[n][4*p + 2]), gelu_erf(acc[n][4*p + 3]));
                sttf(t_lds, row_l, f * 2 + n, p, kg, w);
            }
    }
    __syncthreads();

    // ================= stage 2: swapped, K=256, LDS in-place =================
    {
        f32x16 acc[2];
        acc[0] = (f32x16)0.0f; acc[1] = (f32x16)0.0f;

        #pragma unroll
        for (int ks = 0; ks < 16; ++ks) {
            bf16x8 tf = ldtf(t_lds, row_l, ks, kg);
            #pragma unroll
            for (int n = 0; n < 2; ++n) {
                bf16x8 wf = ldw(w2s, ks, f * 2 + n, kg, l31);
                acc[n] = __builtin_amdgcn_mfma_f32_32x32x16_bf16(wf, tf, acc[n], 0, 0, 0);
            }
        }
        __syncthreads();   // all reads of t1 done before overwrite
        #pragma unroll
        for (int n = 0; n < 2; ++n)
            #pragma unroll
            for (int p = 0; p < 4; ++p) {
                uint2 w;
                w.x = pack2(gelu_erf(acc[n][4*p + 0]), gelu_erf(acc[n][4*p + 1]));
                w.y = pack2(gelu_erf(acc[n][4*p + 2]), gelu_erf(acc[n][4*p + 3]));
                sttf(t_lds, row_l, f * 2 + n, p, kg, w);
            }
    }
    __syncthreads();

    // ================= stage 3: normal, K=256, feat prefetched =================
    {
        f32x16 acc[2];
        acc[0] = (f32x16)0.0f; acc[1] = (f32x16)0.0f;
        float ft[16][2];

        // prefetch feat for first 8 output rows (issues before MFMA loop)
        #pragma unroll
        for (int r = 0; r < 8; ++r) {
            const int lrow = (r & 3) + 8 * (r >> 2) + 4 * kg;
            const int sv = __shfl(src0, lrow);
            const float* fp = feat + (size_t)sv * 256 + f * 64 + l31;
            ft[r][0] = fp[0];
            ft[r][1] = fp[32];
        }

        #pragma unroll
        for (int ks = 0; ks < 16; ++ks) {
            if (ks == 8) {
                // second half of feat prefetch (hidden under remaining MFMAs)
                #pragma unroll
                for (int r = 8; r < 16; ++r) {
                    const int lrow = (r & 3) + 8 * (r >> 2) + 4 * kg;
                    const int sv = __shfl(src0, lrow);
                    const float* fp = feat + (size_t)sv * 256 + f * 64 + l31;
                    ft[r][0] = fp[0];
                    ft[r][1] = fp[32];
                }
            }
            bf16x8 tf = ldtf(t_lds, row_l, ks, kg);
            #pragma unroll
            for (int n = 0; n < 2; ++n) {
                bf16x8 wf = ldw(w3s, ks, f * 2 + n, kg, l31);
                acc[n] = __builtin_amdgcn_mfma_f32_32x32x16_bf16(tf, wf, acc[n], 0, 0, 0);
            }
        }

        // epilogue: packed b32 stores, column-permuted within the f-quarter
        #pragma unroll
        for (int r = 0; r < 16; ++r) {
            const int lrow = (r & 3) + 8 * (r >> 2) + 4 * kg;
            const int gi = blk0 + g * 32 + lrow;
            if (gi < E) {
                float gav = __shfl(gva, lrow);
                float gbv = __shfl(gvb, lrow);
                float v0 = ft[r][0] * gav + acc[0][r] * gbv;
                float v1 = ft[r][1] * gav + acc[1][r] * gbv;
                *(unsigned*)(m + (size_t)gi * 256 + f * 64 + l31 * 2) = pack2(v0, v1);
            }
        }
    }
}

// ---------------- segment sum over sorted m: one wave per dst ----------------
__global__ __launch_bounds__(256) void segsum_kernel(
    const int* __restrict__ start, const unsigned short* __restrict__ m,
    unsigned short* __restrict__ h, int ND)
{
    int d = blockIdx.x * 4 + (threadIdx.x >> 6);
    if (d >= ND) return;
    int lane = threadIdx.x & 63;
    int s0 = start[d], s1 = start[d + 1];
    float a0 = 0.f, a1 = 0.f, a2 = 0.f, a3 = 0.f;
    for (int i = s0; i < s1; ++i) {
        ushort4 v = *(const ushort4*)(m + (size_t)i * 256 + lane * 4);
        a0 += bf2f(v.x); a1 += bf2f(v.y); a2 += bf2f(v.z); a3 += bf2f(v.w);
    }
    ushort4 o; o.x = f2bf(a0); o.y = f2bf(a1); o.z = f2bf(a2); o.w = f2bf(a3);
    *(ushort4*)(h + (size_t)d * 256 + lane * 4) = o;
}

// ---------------- g4: out = (h @ lin_w^T)*ci + b (perm baked into lws) ----------------
__global__ __launch_bounds__(256, 2) void g4_kernel(
    const unsigned short* __restrict__ Ab, const unsigned short* __restrict__ lws,
    float* __restrict__ outf, const float* __restrict__ ci,
    const float* __restrict__ bias, int M)
{
    const int lane = threadIdx.x & 63;
    const int wid  = threadIdx.x >> 6;
    const int l31  = lane & 31;
    const int kg   = lane >> 5;
    const int f    = wid & 1;                 // column half
    const int wbase = blockIdx.x * 128 + (wid >> 1) * 64;
    const int r0 = wbase + l31, r1 = wbase + 32 + l31;
    const int ar0 = (r0 < M) ? r0 : (M - 1);
    const int ar1 = (r1 < M) ? r1 : (M - 1);

    f32x16 acc[2][4];
    #pragma unroll
    for (int mi = 0; mi < 2; ++mi)
        #pragma unroll
        for (int n = 0; n < 4; ++n) acc[mi][n] = (f32x16)0.0f;

    #pragma unroll
    for (int ks = 0; ks < 16; ++ks) {
        const int kk = ks * 16 + kg * 8;
        bf16x8 a0 = *(const bf16x8*)(Ab + (size_t)ar0 * 256 + kk);
        bf16x8 a1 = *(const bf16x8*)(Ab + (size_t)ar1 * 256 + kk);
        #pragma unroll
        for (int n = 0; n < 4; ++n) {
            bf16x8 b = ldw(lws, ks, f * 4 + n, kg, l31);
            acc[0][n] = __builtin_amdgcn_mfma_f32_32x32x16_bf16(a0, b, acc[0][n], 0, 0, 0);
            acc[1][n] = __builtin_amdgcn_mfma_f32_32x32x16_bf16(a1, b, acc[1][n], 0, 0, 0);
        }
    }
    #pragma unroll
    for (int mi = 0; mi < 2; ++mi) {
        #pragma unroll
        for (int r = 0; r < 16; ++r) {
            const int gr = wbase + mi * 32 + (r & 3) + 8 * (r >> 2) + 4 * kg;
            if (gr >= M) continue;
            float civ = ci[gr];
            #pragma unroll
            for (int n = 0; n < 4; ++n) {
                int col = f * 128 + n * 32 + l31;
                outf[(size_t)gr * 256 + col] = acc[mi][n][r] * civ + bias[col];
            }
        }
    }
}

extern "C" void kernel_launch(void* const* d_in, const int* in_sizes, int n_in,
                              void* d_out, int out_size, void* d_ws, size_t ws_size,
                              hipStream_t stream) {
    const float* feat = (const float*)d_in[0];
    const float* cj   = (const float*)d_in[1];
    const float* ci   = (const float*)d_in[2];
    const int*   esrc = (const int*)d_in[3];
    const int*   edst = (const int*)d_in[4];
    const int*   rid  = (const int*)d_in[5];
    const float* remb = (const float*)d_in[6];
    const float* pw   = (const float*)d_in[7];
    const float* sw   = (const float*)d_in[8];
    const float* rw1  = (const float*)d_in[9];
    const float* rw2  = (const float*)d_in[10];
    const float* rw3  = (const float*)d_in[11];
    const float* lw   = (const float*)d_in[12];
    const float* lb   = (const float*)d_in[13];
    float* out = (float*)d_out;

    const int E  = in_sizes[3];   // 300000
    const int ND = in_sizes[2];   // 100000

    // workspace carve-up (~211 MB)
    char* ws = (char*)d_ws;
    unsigned short* m   = (unsigned short*)ws;            // E*256 bf16 (permuted cols)
    unsigned short* h   = m + (size_t)E * 256;            // ND*256 bf16 (permuted cols)
    unsigned short* w1s = h + (size_t)ND * 256;           // 32768
    unsigned short* w2s = w1s + 32768;                    // 65536
    unsigned short* w3s = w2s + 65536;                    // 65536
    unsigned short* lws = w3s + 65536;                    // 65536
    int* cnt    = (int*)(lws + 65536);                    // ND
    int* start  = cnt + ND;                               // ND+1
    int* bsum   = start + ND + 1;                         // 128
    int* within = bsum + 128;                             // E
    int* eidx   = within + E;                             // E
    int* rid_s  = eidx + E;                               // E
    int* esrc_s = rid_s + E;                              // E

    const int NB = (ND + 1023) / 1024;

    hipMemsetAsync(cnt, 0, (size_t)ND * sizeof(int), stream);
    prep_weights<<<256, 256, 0, stream>>>(rw1, rw2, rw3, lw, w1s, w2s, w3s, lws);

    // CSR build + sorted-edge gathers
    hist_kernel<<<(E + 255) / 256, 256, 0, stream>>>(edst, cnt, within, E);
    scan_block<<<NB, 1024, 0, stream>>>(cnt, start, bsum, ND);
    scan_bsum<<<1, 64, 0, stream>>>(bsum, NB);
    add_offsets<<<NB, 1024, 0, stream>>>(start, bsum, ND, E);
    build_eidx<<<(E + 255) / 256, 256, 0, stream>>>(edst, within, start, eidx, E);
    gather_sorted<<<(E + 255) / 256, 256, 0, stream>>>(eidx, rid, esrc, rid_s, esrc_s, E);

    // fused g1+g2+g3 (8 waves, 64 edges/block, t staged in 32KB LDS)
    fused_edge<<<(E + 63) / 64, 512, 0, stream>>>(
        remb, rid_s, esrc_s, w1s, w2s, w3s, pw, sw, cj, feat, m, E);

    // segsum over contiguous sorted rows
    segsum_kernel<<<(ND + 3) / 4, 256, 0, stream>>>(start, m, h, ND);

    // g4
    g4_kernel<<<(ND + 127) / 128, 256, 0, stream>>>(h, lws, out, ci, lb, ND);
}